// Round 1
// baseline (145.942 us; speedup 1.0000x reference)
//
#include <hip/hip_runtime.h>
#include <math.h>

#define D      1024
#define CD     16
#define CS     8192
#define ROWS   16384   // B*L
#define LN_EPS 1e-5f
#define KCHUNK 512            // codes per dist chunk
#define NCHUNK (CS / KCHUNK)  // 16

typedef __attribute__((ext_vector_type(8))) short short8;
typedef __attribute__((ext_vector_type(4))) float f32x4;
typedef __attribute__((ext_vector_type(16))) float f32x16;

__device__ inline unsigned short bf16_rne(float v) {
    unsigned u = __float_as_uint(v);
    unsigned r = u + 0x7FFFu + ((u >> 16) & 1u);
    return (unsigned short)(r >> 16);
}
__device__ inline short8 ld8(const unsigned short* p) { return *(const short8*)p; }

// exact 3-term bf16 split: v = a + b + c, dropped residual ~2^-27 rel
__device__ inline void split3(float v, unsigned short& a, unsigned short& b, unsigned short& c) {
    unsigned u = __float_as_uint(v);
    unsigned r = u + 0x7FFFu + ((u >> 16) & 1u);
    a = (unsigned short)(r >> 16);
    float r1 = v - __uint_as_float(r & 0xFFFF0000u);     // exact
    unsigned u1 = __float_as_uint(r1);
    unsigned r1b = u1 + 0x7FFFu + ((u1 >> 16) & 1u);
    b = (unsigned short)(r1b >> 16);
    float r2 = r1 - __uint_as_float(r1b & 0xFFFF0000u);  // exact
    c = bf16_rne(r2);
}

// -------------------------------------------------------------------------
// pack: blockIdx < 32 -> codebook 3-term split (48 bf16/code) + -0.5||c||^2;
//       blockIdx >= 32 -> W 3-term split in MFMA-B-frag stream order:
//       wb[((gk*3+term)*64 + lane)*8 + j] = W_t[n=lane&15][gk*32+(lane>>4)*8+j]
// -------------------------------------------------------------------------
__global__ __launch_bounds__(256) void pack_all(const float* __restrict__ W,
                                                const float* __restrict__ cb,
                                                unsigned short* __restrict__ wb,
                                                unsigned short* __restrict__ cbp,
                                                float* __restrict__ nhc)
{
    const int t = threadIdx.x;
    if (blockIdx.x < 32) {
        int k = blockIdx.x * 256 + t;          // 0..8191
        const float* c = cb + (long)k * CD;
        unsigned short* o = cbp + (long)k * 48;
        float csq = 0.f;
        #pragma unroll
        for (int d = 0; d < 16; ++d) {
            float v = c[d];
            csq = fmaf(v, v, csq);
            unsigned short h0, h1, h2;
            split3(v, h0, h1, h2);
            o[d] = h0; o[16 + d] = h1; o[32 + d] = h2;
        }
        nhc[k] = -0.5f * csq;
    } else {
        int tid = (blockIdx.x - 32) * 256 + t; // 0..6143
        int gk   = tid / 192;
        int rem  = tid % 192;
        int term = rem >> 6;
        int L    = rem & 63;
        int n = L & 15, q = L >> 4;
        const float* src = W + n * D + gk * 32 + q * 8;
        unsigned short* dst = wb + (size_t)tid * 8;
        #pragma unroll
        for (int j = 0; j < 8; ++j) {
            unsigned short h0, h1, h2;
            split3(src[j], h0, h1, h2);
            dst[j] = term == 0 ? h0 : (term == 1 ? h1 : h2);
        }
    }
}

// -------------------------------------------------------------------------
// proj_ln: z = LayerNorm(x @ W^T) fused, emitted as 3-term bf16 split.
// Block = 4 waves = 1 row-tile x 4 K-quarters (256 k each). Grid 1024 ->
// 4 blocks/CU, 16 waves/CU, exactly one resident generation.
// Per wave: 8 kk steps of 6 MFMAs (exact 3-term split both sides), split
// across TWO independent accumulator chains for MFMA-latency hiding.
// K-quarters combined via 3KB LDS; LN over 16 channels (quad lanes) by
// shfl_xor; split3 + store zp in dist A-frag order.
// -------------------------------------------------------------------------
__global__ __launch_bounds__(256, 4) void proj_ln(const float* __restrict__ x,
                                                  const unsigned short* __restrict__ wb,
                                                  unsigned short* __restrict__ zp)
{
    __shared__ float part[3][64][4];   // waves 1..3 deposit here
    const int t = threadIdx.x;
    const int L = t & 63;
    const int kq = t >> 6;             // K-quarter
    const int rt = blockIdx.x;         // row-tile
    const int n = L & 15, q = L >> 4;

    const float* xrow = x + (size_t)(rt * 16 + n) * D + kq * 256 + q * 8;
    const unsigned short* wbase = wb + (size_t)(kq * 8) * 1536;

    f32x4 acc0 = {0.f, 0.f, 0.f, 0.f};
    f32x4 acc1 = {0.f, 0.f, 0.f, 0.f};
    #pragma unroll
    for (int kk = 0; kk < 8; ++kk) {
        float4 xa = *(const float4*)(xrow + kk * 32);
        float4 xb = *(const float4*)(xrow + kk * 32 + 4);
        const unsigned short* wp = wbase + (size_t)kk * 1536 + L * 8;
        short8 w0 = ld8(wp);
        short8 w1 = ld8(wp + 512);
        short8 w2 = ld8(wp + 1024);
        float vs[8] = {xa.x, xa.y, xa.z, xa.w, xb.x, xb.y, xb.z, xb.w};
        short8 x0, x1, x2;
        #pragma unroll
        for (int j = 0; j < 8; ++j) {
            unsigned short h0, h1, h2;
            split3(vs[j], h0, h1, h2);
            x0[j] = (short)h0; x1[j] = (short)h1; x2[j] = (short)h2;
        }
        // two independent chains (exact products >= 2^-24 kept on each)
        acc0 = __builtin_amdgcn_mfma_f32_16x16x32_bf16(x0, w0, acc0, 0, 0, 0);
        acc1 = __builtin_amdgcn_mfma_f32_16x16x32_bf16(x0, w1, acc1, 0, 0, 0);
        acc0 = __builtin_amdgcn_mfma_f32_16x16x32_bf16(x1, w0, acc0, 0, 0, 0);
        acc1 = __builtin_amdgcn_mfma_f32_16x16x32_bf16(x1, w1, acc1, 0, 0, 0);
        acc0 = __builtin_amdgcn_mfma_f32_16x16x32_bf16(x0, w2, acc0, 0, 0, 0);
        acc1 = __builtin_amdgcn_mfma_f32_16x16x32_bf16(x2, w0, acc1, 0, 0, 0);
    }

    if (kq != 0) {
        #pragma unroll
        for (int r = 0; r < 4; ++r) part[kq - 1][L][r] = acc0[r] + acc1[r];
    }
    __syncthreads();
    if (kq == 0) {
        // C/D layout: col n = channel (lane&15), row = q*4 + r
        #pragma unroll
        for (int r = 0; r < 4; ++r) {
            float zv = acc0[r] + acc1[r] + part[0][L][r] + part[1][L][r] + part[2][L][r];
            float s = zv;
            for (int m = 1; m < 16; m <<= 1) s += __shfl_xor(s, m, 64);
            float mu = s * (1.f / 16.f);
            float dd = zv - mu;
            float v2 = dd * dd;
            for (int m = 1; m < 16; m <<= 1) v2 += __shfl_xor(v2, m, 64);
            float var = v2 * (1.f / 16.f);
            float zn = dd / sqrtf(var + LN_EPS);
            unsigned short h0, h1, h2;
            split3(zn, h0, h1, h2);
            unsigned short* zr = zp + (size_t)(rt * 16 + q * 4 + r) * 48;
            zr[n] = h0; zr[16 + n] = h1; zr[32 + n] = h2;
        }
    }
}

// -------------------------------------------------------------------------
// dist_argmin: score = z.c - 0.5||c||^2 (argmin d2 == argmax score).
// 32x32x16 MFMA variant: K=16 == CD, so the exact 6-product split maps to
// 6 clean MFMAs per 32x32 tile (z0c0,z1c1,z1c0,z0c1,z2c0,z0c2) -- same
// FLOPs as the 16x16 path but at the faster 32x32 pipe rate and half the
// instruction issues. A: m=lane&31 (z row), k=(lane>>5)*8+j. B: n=lane&31
// (code), k=(lane>>5)*8+j. C/D (HW-verified): col=lane&31,
// row=(reg&3)+8*(reg>>2)+4*(lane>>5). Per lane all 16 acc elems share one
// code -> scalar bi update. Bias enters as the C operand of the 1st MFMA.
// Block = 8 waves x one 32-row tile each = 256 rows; grid 64x16 unchanged,
// 2 blocks/CU.
// -------------------------------------------------------------------------
__global__ __launch_bounds__(512, 4) void dist_argmin(const unsigned short* __restrict__ zp,
                                                      const unsigned short* __restrict__ cbp,
                                                      const float* __restrict__ nhc,
                                                      float* __restrict__ pbest,
                                                      int* __restrict__ pidx)
{
    __shared__ __align__(16) unsigned short cl[KCHUNK * 48];  // 48 KB
    __shared__ float ql[KCHUNK];                              // 2 KB
    const int t = threadIdx.x;
    const int kbase = blockIdx.y * KCHUNK;

    {
        float4* dst = (float4*)cl;
        const float4* src = (const float4*)(cbp + (size_t)kbase * 48);
        #pragma unroll
        for (int i = 0; i < 6; ++i) dst[t + i * 512] = src[t + i * 512];
        if (t < KCHUNK / 4) ((float4*)ql)[t] = ((const float4*)(nhc + kbase))[t];
    }
    __syncthreads();

    const int L = t & 63;
    const int w = t >> 6;
    const int c31 = L & 31;    // code col (B n) / z row (A m)
    const int half = L >> 5;   // k-half selector

    const int rt = blockIdx.x * 8 + w;   // 32-row tile index (512 total)
    const unsigned short* zr = zp + (size_t)(rt * 32 + c31) * 48 + half * 8;
    short8 a0 = ld8(zr);        // z term-0 fragment
    short8 a1 = ld8(zr + 16);   // z term-1
    short8 a2 = ld8(zr + 32);   // z term-2

    float best[16];
    int   bi[16];
    #pragma unroll
    for (int r = 0; r < 16; ++r) { best[r] = -INFINITY; bi[r] = 0; }

    #pragma unroll 2
    for (int tt = 0; tt < KCHUNK / 32; ++tt) {
        const unsigned short* cp = cl + (size_t)(tt * 32 + c31) * 48 + half * 8;
        short8 b0 = ld8(cp);
        short8 b1 = ld8(cp + 16);
        short8 b2 = ld8(cp + 32);
        float bneg = ql[tt * 32 + c31];
        int code = kbase + tt * 32 + c31;
        f32x16 acc;
        #pragma unroll
        for (int r = 0; r < 16; ++r) acc[r] = bneg;
        acc = __builtin_amdgcn_mfma_f32_32x32x16_bf16(a0, b0, acc, 0, 0, 0);
        acc = __builtin_amdgcn_mfma_f32_32x32x16_bf16(a1, b1, acc, 0, 0, 0);
        acc = __builtin_amdgcn_mfma_f32_32x32x16_bf16(a1, b0, acc, 0, 0, 0);
        acc = __builtin_amdgcn_mfma_f32_32x32x16_bf16(a0, b1, acc, 0, 0, 0);
        acc = __builtin_amdgcn_mfma_f32_32x32x16_bf16(a2, b0, acc, 0, 0, 0);
        acc = __builtin_amdgcn_mfma_f32_32x32x16_bf16(a0, b2, acc, 0, 0, 0);
        #pragma unroll
        for (int r = 0; r < 16; ++r)
            if (acc[r] > best[r]) { best[r] = acc[r]; bi[r] = code; }
    }

    // reduce best over the 32 codes held by lanes within each 32-lane half
    #pragma unroll
    for (int mask = 1; mask < 32; mask <<= 1) {
        #pragma unroll
        for (int r = 0; r < 16; ++r) {
            float s2 = __shfl_xor(best[r], mask, 64);
            int   i2 = __shfl_xor(bi[r], mask, 64);
            if (s2 > best[r] || (s2 == best[r] && i2 < bi[r])) {
                best[r] = s2; bi[r] = i2;
            }
        }
    }
    if (c31 == 0) {
        #pragma unroll
        for (int r = 0; r < 16; ++r) {
            int row = rt * 32 + (r & 3) + 8 * (r >> 2) + 4 * half;
            pbest[(size_t)row * NCHUNK + blockIdx.y] = best[r];
            pidx [(size_t)row * NCHUNK + blockIdx.y] = bi[r];
        }
    }
}

// -------------------------------------------------------------------------
// merge: fold 16 partials/row; ascending chunk order + strict '>' keeps the
// earliest winner -> matches np first-min argmin.
// -------------------------------------------------------------------------
__global__ __launch_bounds__(256) void merge_argmin(const float* __restrict__ pbest,
                                                    const int* __restrict__ pidx,
                                                    int* __restrict__ out)
{
    const long row = (long)blockIdx.x * 256 + threadIdx.x;
    float best = -INFINITY;
    int   bi   = 0;
    #pragma unroll
    for (int i = 0; i < NCHUNK; ++i) {
        float s = pbest[row * NCHUNK + i];
        if (s > best) { best = s; bi = pidx[row * NCHUNK + i]; }
    }
    out[row] = bi;
}

// -------------------------------------------------------------------------
extern "C" void kernel_launch(void* const* d_in, const int* in_sizes, int n_in,
                              void* d_out, int out_size, void* d_ws, size_t ws_size,
                              hipStream_t stream)
{
    const float* x  = (const float*)d_in[0];   // 8*2048*1024
    const float* W  = (const float*)d_in[1];   // 16*1024
    const float* cb = (const float*)d_in[2];   // 8192*16
    int* out = (int*)d_out;                    // 16384 int32

    char* ws = (char*)d_ws;
    unsigned short* zp  = (unsigned short*)ws;               // 1.5 MB
    unsigned short* cbp = (unsigned short*)(ws + 0x180000);  // 768 KB
    float* nhc  = (float*)(ws + 0x240000);                   // 32 KB
    unsigned short* wb = (unsigned short*)(ws + 0x248000);   // 96 KB
    float* pbest = (float*)(ws + 0x260000);                  // 1 MB
    int*   pidx  = (int*)  (ws + 0x360000);                  // 1 MB

    pack_all<<<56, 256, 0, stream>>>(W, cb, wb, cbp, nhc);
    proj_ln <<<ROWS / 16, 256, 0, stream>>>(x, wb, zp);
    dist_argmin<<<dim3(ROWS / 256, NCHUNK), 512, 0, stream>>>(zp, cbp, nhc, pbest, pidx);
    merge_argmin<<<ROWS / 256, 256, 0, stream>>>(pbest, pidx, out);
}